// Round 8
// baseline (107.212 us; speedup 1.0000x reference)
//
#include <hip/hip_runtime.h>

typedef unsigned short ushort_t;
typedef __attribute__((ext_vector_type(8))) short bfrag;
typedef __attribute__((ext_vector_type(4))) float f4;

// B=4, D=256, H=W=64, num_levels=4, radius=4
#define NB 4
#define ND 256
#define NH 64
#define NW 64
#define NQ (NH * NW)            // 4096 queries per batch
#define MPAD 5632               // 22 * 256 rows of pooled-f2 features (5440 real)
#define NLVL 4
#define NCH (NLVL * 81)

__device__ __forceinline__ float bf2f(ushort_t u) {
    return __uint_as_float(((unsigned)u) << 16);
}
__device__ __forceinline__ ushort_t f2bf(float f) {
    unsigned u = __float_as_uint(f);
    unsigned r = (u + 0x7fffu + ((u >> 16) & 1u)) >> 16;
    return (ushort_t)r;
}

__device__ __forceinline__ void gload_lds16(const void* g, void* l) {
    __builtin_amdgcn_global_load_lds(
        (const __attribute__((address_space(1))) unsigned int*)g,
        (__attribute__((address_space(3))) unsigned int*)l, 16, 0, 0);
}

// ---------- kernel 1: transpose [b][256][4096] f32 -> [b][n][256] bf16 (opt. scale) ----------
__global__ __launch_bounds__(256) void transpose_cvt(
    const float* __restrict__ in, ushort_t* __restrict__ outp,
    size_t in_bstride, size_t out_bstride, float scale)
{
    __shared__ float tile[64][65];
    const int tid = threadIdx.x;
    const int n0 = blockIdx.x * 64, d0 = blockIdx.y * 64, b = blockIdx.z;
    const float* ib = in + (size_t)b * in_bstride;
    ushort_t* ob = outp + (size_t)b * out_bstride;
    const int nl = tid & 63, dg = tid >> 6;
#pragma unroll
    for (int i = 0; i < 16; i++) {
        int dl = dg + i * 4;
        tile[dl][nl] = ib[(size_t)(d0 + dl) * NQ + n0 + nl];
    }
    __syncthreads();
    const int dl = tid & 63, ng = tid >> 6;
#pragma unroll
    for (int i = 0; i < 16; i++) {
        int nn = ng + i * 4;
        ob[(size_t)(n0 + nn) * ND + d0 + dl] = f2bf(tile[dl][nn] * scale);
    }
}

// ---------- kernel 2: avg-pool 2x2 in [m][d] bf16 layout (cascade) ----------
__global__ void pool_kernel(ushort_t* __restrict__ Ball, int Wlo, int in_off, int out_off)
{
    int t = blockIdx.x * 256 + threadIdx.x;
    int d = t & 255;
    int rest = t >> 8;
    int Nl = Wlo * Wlo;
    int m = rest % Nl;
    int b = rest / Nl;
    if (b >= NB) return;
    int y = m / Wlo, x = m - y * Wlo;
    int Wi = Wlo * 2;
    const ushort_t* src = Ball + (size_t)b * MPAD * ND;
    float s = 0.f;
#pragma unroll
    for (int iy = 0; iy < 2; iy++)
#pragma unroll
        for (int ix = 0; ix < 2; ix++)
            s += bf2f(src[(size_t)(in_off + (2 * y + iy) * Wi + (2 * x + ix)) * ND + d]);
    Ball[(size_t)b * MPAD * ND + (size_t)(out_off + m) * ND + d] = f2bf(s * 0.25f);
}

// ---------- kernel 2b: per-(batch,level,query) integer window base table ----------
__global__ void make_tbl(const float* __restrict__ coords, int* __restrict__ tbl)
{
    int t = blockIdx.x * 256 + threadIdx.x;     // b*4096 + q
    int b = t >> 12, q = t & 4095;
    float cx = coords[((size_t)b * 2 + 0) * NQ + q];
    float cy = coords[((size_t)b * 2 + 1) * NQ + q];
#pragma unroll
    for (int lvl = 0; lvl < 4; lvl++) {
        float s = 1.0f / (float)(1 << lvl);
        int x0 = (int)floorf(cx * s);
        int y0 = (int)floorf(cy * s);
        tbl[((b * 4 + lvl) << 12) + q] = (x0 & 0xffff) | (y0 << 16);
    }
}

// ---------- kernel 3: 256x256 8-wave 8-phase (4 phases/K-tile) bf16 MFMA GEMM ----------
// grid.x = 1408 = 4 batches * 16 M-tiles * 22 N-tiles, XCD-swizzled
__global__ __launch_bounds__(512, 2) void gemm_corr(
    const ushort_t* __restrict__ A,     // [NB][4096][256] bf16 (pre-scaled by 1/16)
    const ushort_t* __restrict__ Bm,    // [NB][MPAD][256] bf16
    ushort_t* __restrict__ compact,     // [NB][4096][400] bf16
    const int* __restrict__ tbl)        // [NB][4][4096] packed (x0,y0)
{
    // A: 2 dbuf slots of [256][64] bf16 at d*16384; B same at 32768 + d*16384
    __shared__ ushort_t SM[65536];      // 128 KiB

    // bijective XCD-chunk swizzle: 1408 = 8 * 176
    const int l   = blockIdx.x;
    const int wg  = (l & 7) * 176 + (l >> 3);
    const int z   = wg / 352;
    const int rem = wg - z * 352;
    const int by  = rem / 22;
    const int bxt = rem - by * 22;

    const int tid  = threadIdx.x;
    const int lane = tid & 63;
    const int wv   = tid >> 6;       // 0..7
    const int wm   = wv >> 2;        // M-half (rows wm*128..+128)
    const int wn   = wv & 3;         // N-quarter (cols wn*64..+64)
    const int ln15 = lane & 15;
    const int g4   = lane >> 4;      // 0..3
    const int swz  = ln15 & 7;

    const ushort_t* Ab = A  + ((size_t)z * NQ   + (size_t)by * 256) * ND;
    const ushort_t* Bb = Bm + ((size_t)z * MPAD + (size_t)bxt * 256) * ND;

    // ---- staging maps (linear LDS dest, inverse-swizzled global source) ----
    // A quarter (64 rows x 64 K = 8 KB): 1 load/thread
    const int qA = wv * 64 + lane;               // 0..511
    const int rA = qA >> 3;                      // row within quarter
    const int cA = (qA & 7) ^ (rA & 7);          // inverse-swizzled chunk
    const ushort_t* srcA = Ab + (size_t)rA * ND + cA * 8;
    const int dstA = qA * 8;
    // B half (128 rows x 64 K = 16 KB): 2 loads/thread
    const int qB0 = wv * 128 + lane, qB1 = qB0 + 64;   // 0..1023
    const int rB0 = qB0 >> 3, rB1 = qB1 >> 3;
    const int cB0 = (qB0 & 7) ^ (rB0 & 7), cB1 = (qB1 & 7) ^ (rB1 & 7);
    const ushort_t* srcB0 = Bb + (size_t)rB0 * ND + cB0 * 8;
    const ushort_t* srcB1 = Bb + (size_t)rB1 * ND + cB1 * 8;
    const int dstB0 = qB0 * 8, dstB1 = qB1 * 8;

#define ST_A(dd, qd, T) gload_lds16(srcA + ((qd) * 64 * ND + (T) * 64),            \
                                    &SM[(dd) * 16384 + (qd) * 4096 + dstA])
#define ST_B(dd, h, T)  { gload_lds16(srcB0 + ((h) * 128 * ND + (T) * 64),         \
                              &SM[32768 + (dd) * 16384 + (h) * 8192 + dstB0]);     \
                          gload_lds16(srcB1 + ((h) * 128 * ND + (T) * 64),         \
                              &SM[32768 + (dd) * 16384 + (h) * 8192 + dstB1]); }

    // ---- swizzled fragment read bases (ushort indices, sans slot/frag offset) ----
    const int aadr0 = (wm * 128 + ln15) * 64 + ((g4    ) ^ swz) * 8;   // k-slice 0
    const int aadr1 = (wm * 128 + ln15) * 64 + ((4 + g4) ^ swz) * 8;   // k-slice 1
    const int badr0 = 32768 + (wn * 64 + ln15) * 64 + ((g4    ) ^ swz) * 8;
    const int badr1 = 32768 + (wn * 64 + ln15) * 64 + ((4 + g4) ^ swz) * 8;

    f4 acc[8][4] = {};

    // ---- prologue: stage K-tile 0 into slot 0 (order matches steady-state) ----
    ST_B(0, 0, 0); ST_B(0, 1, 0);
    ST_A(0, 0, 0); ST_A(0, 2, 0);
    ST_A(0, 1, 0); ST_A(0, 3, 0);

#pragma unroll
    for (int T = 0; T < 4; ++T) {
        const int d = T & 1, e = d ^ 1;
        bfrag a[4], b[4];

        // ======== phase 0: A(mi 0-3) ks0 + B ks0 ========
        asm volatile("s_waitcnt vmcnt(2)" ::: "memory");
        __builtin_amdgcn_s_barrier();
        asm volatile("" ::: "memory");
#pragma unroll
        for (int mi = 0; mi < 4; mi++)
            a[mi] = *reinterpret_cast<const bfrag*>(&SM[d * 16384 + aadr0 + mi * 1024]);
#pragma unroll
        for (int ni = 0; ni < 4; ni++)
            b[ni] = *reinterpret_cast<const bfrag*>(&SM[d * 16384 + badr0 + ni * 1024]);
        if (T < 3) ST_B(e, 0, T + 1);
        asm volatile("s_waitcnt lgkmcnt(0)" ::: "memory");
        __builtin_amdgcn_sched_barrier(0);
        __builtin_amdgcn_s_setprio(1);
#pragma unroll
        for (int mi = 0; mi < 4; mi++)
#pragma unroll
            for (int ni = 0; ni < 4; ni++)
                acc[mi][ni] = __builtin_amdgcn_mfma_f32_16x16x32_bf16(
                    a[mi], b[ni], acc[mi][ni], 0, 0, 0);
        __builtin_amdgcn_s_setprio(0);

        // ======== phase 1: A(mi 4-7) ks0 (B reused) ========
        if (T < 3) { asm volatile("s_waitcnt vmcnt(2)" ::: "memory"); }
        else       { asm volatile("s_waitcnt vmcnt(0)" ::: "memory"); }
        __builtin_amdgcn_s_barrier();
        asm volatile("" ::: "memory");
#pragma unroll
        for (int mi = 0; mi < 4; mi++)
            a[mi] = *reinterpret_cast<const bfrag*>(&SM[d * 16384 + aadr0 + (mi + 4) * 1024]);
        if (T < 3) ST_B(e, 1, T + 1);
        asm volatile("s_waitcnt lgkmcnt(0)" ::: "memory");
        __builtin_amdgcn_sched_barrier(0);
        __builtin_amdgcn_s_setprio(1);
#pragma unroll
        for (int mi = 0; mi < 4; mi++)
#pragma unroll
            for (int ni = 0; ni < 4; ni++)
                acc[mi + 4][ni] = __builtin_amdgcn_mfma_f32_16x16x32_bf16(
                    a[mi], b[ni], acc[mi + 4][ni], 0, 0, 0);
        __builtin_amdgcn_s_setprio(0);

        // ======== phase 2: A(mi 0-3) ks1 + B ks1 ========
        __builtin_amdgcn_s_barrier();
        asm volatile("" ::: "memory");
#pragma unroll
        for (int mi = 0; mi < 4; mi++)
            a[mi] = *reinterpret_cast<const bfrag*>(&SM[d * 16384 + aadr1 + mi * 1024]);
#pragma unroll
        for (int ni = 0; ni < 4; ni++)
            b[ni] = *reinterpret_cast<const bfrag*>(&SM[d * 16384 + badr1 + ni * 1024]);
        if (T < 3) { ST_A(e, 0, T + 1); ST_A(e, 2, T + 1); }
        asm volatile("s_waitcnt lgkmcnt(0)" ::: "memory");
        __builtin_amdgcn_sched_barrier(0);
        __builtin_amdgcn_s_setprio(1);
#pragma unroll
        for (int mi = 0; mi < 4; mi++)
#pragma unroll
            for (int ni = 0; ni < 4; ni++)
                acc[mi][ni] = __builtin_amdgcn_mfma_f32_16x16x32_bf16(
                    a[mi], b[ni], acc[mi][ni], 0, 0, 0);
        __builtin_amdgcn_s_setprio(0);

        // ======== phase 3: A(mi 4-7) ks1 ========
        __builtin_amdgcn_s_barrier();
        asm volatile("" ::: "memory");
#pragma unroll
        for (int mi = 0; mi < 4; mi++)
            a[mi] = *reinterpret_cast<const bfrag*>(&SM[d * 16384 + aadr1 + (mi + 4) * 1024]);
        if (T < 3) { ST_A(e, 1, T + 1); ST_A(e, 3, T + 1); }
        asm volatile("s_waitcnt lgkmcnt(0)" ::: "memory");
        __builtin_amdgcn_sched_barrier(0);
        __builtin_amdgcn_s_setprio(1);
#pragma unroll
        for (int mi = 0; mi < 4; mi++)
#pragma unroll
            for (int ni = 0; ni < 4; ni++)
                acc[mi + 4][ni] = __builtin_amdgcn_mfma_f32_16x16x32_bf16(
                    a[mi], b[ni], acc[mi + 4][ni], 0, 0, 0);
        __builtin_amdgcn_s_setprio(0);
    }
#undef ST_A
#undef ST_B

    // ---- compacted epilogue, geometry-aware per level (256-wide tiles) ----
    int lvl;
    if (bxt < 16)      lvl = 0;
    else if (bxt < 20) lvl = 1;
    else if (bxt < 21) lvl = 2;
    else               lvl = 3;

    const int row0 = by * 256 + wm * 128 + (g4 << 2);
    const int* tb  = tbl + (((size_t)z * 4 + lvl) << 12);
    ushort_t* cmp  = compact + (size_t)z * NQ * 400 + lvl * 100;

    auto for_q = [&](auto body) {
#pragma unroll
        for (int mi = 0; mi < 8; mi++) {
            const int q0 = row0 + mi * 16;
            const int4 xy4 = *reinterpret_cast<const int4*>(&tb[q0]);
            const int xys[4] = {xy4.x, xy4.y, xy4.z, xy4.w};
#pragma unroll
            for (int j = 0; j < 4; j++) {
                const int xy = xys[j];
                body(mi, j, xy & 0xffff, xy >> 16, (size_t)(q0 + j) * 400);
            }
        }
    };

    if (lvl == 0) {
        const int yfix = bxt * 4 + wn;           // y constant per wave
        for_q([&](int mi, int j, int x0, int y0, size_t qb) {
            unsigned v = (unsigned)(yfix - y0 + 4);
            if (v < 10u) {
                size_t vb = qb + v * 10;
#pragma unroll
                for (int ni = 0; ni < 4; ni++) {
                    unsigned u = (unsigned)(ln15 + 16 * ni + 4 - x0);
                    if (u < 10u) cmp[vb + u] = f2bf(acc[mi][ni][j]);
                }
            }
        });
    } else if (lvl == 1) {
        const int ybase = (bxt - 16) * 8 + wn * 2;
        for_q([&](int mi, int j, int x0, int y0, size_t qb) {
            unsigned u0 = (unsigned)(ln15 + 4 - x0), u1 = u0 + 16u;
            unsigned v0 = (unsigned)(ybase - y0 + 4), v1 = v0 + 1u;
            if (v0 < 10u) {
                if (u0 < 10u) cmp[qb + v0 * 10 + u0] = f2bf(acc[mi][0][j]);
                if (u1 < 10u) cmp[qb + v0 * 10 + u1] = f2bf(acc[mi][1][j]);
            }
            if (v1 < 10u) {
                if (u0 < 10u) cmp[qb + v1 * 10 + u0] = f2bf(acc[mi][2][j]);
                if (u1 < 10u) cmp[qb + v1 * 10 + u1] = f2bf(acc[mi][3][j]);
            }
        });
    } else if (lvl == 2) {
        const int ybase = wn * 4;                // bxt==20 covers the whole level
        for_q([&](int mi, int j, int x0, int y0, size_t qb) {
            unsigned u = (unsigned)(ln15 + 4 - x0);
            if (u < 10u) {
#pragma unroll
                for (int ni = 0; ni < 4; ni++) {
                    unsigned v = (unsigned)(ybase + ni - y0 + 4);
                    if (v < 10u) cmp[qb + v * 10 + u] = f2bf(acc[mi][ni][j]);
                }
            }
        });
    } else if (wn == 0) {                        // lvl 3: cols 0..63 (wn>0 = pad)
        const int yb3 = ln15 >> 3;
        for_q([&](int mi, int j, int x0, int y0, size_t qb) {
            unsigned u = (unsigned)((ln15 & 7) + 4 - x0);
            if (u < 10u) {
#pragma unroll
                for (int ni = 0; ni < 4; ni++) {
                    unsigned v = (unsigned)(yb3 + 2 * ni - y0 + 4);
                    if (v < 10u) cmp[qb + v * 10 + u] = f2bf(acc[mi][ni][j]);
                }
            }
        });
    }
}

// ---------- kernel 4: bilinear sampling from the compact window buffer ----------
__global__ __launch_bounds__(256) void sample_kernel(
    const ushort_t* __restrict__ compact,  // [NB][4096][400] bf16
    const float* __restrict__ coords,
    float* __restrict__ out)               // [NB][324][64][64] f32
{
    __shared__ int   X0s[16], Y0s[16];
    __shared__ float wxs[16], wys[16];
    __shared__ float Dl[16 * 101];
    const int tid = threadIdx.x;
    const int g   = blockIdx.x;
    const int lvl = blockIdx.y;
    const int b   = blockIdx.z;
    const int Wl  = NW >> lvl;

    if (tid < 16) {
        int q = g * 16 + tid;
        float cx = coords[(size_t)(b * 2 + 0) * NQ + q];
        float cy = coords[(size_t)(b * 2 + 1) * NQ + q];
        float s = 1.0f / (float)(1 << lvl);
        float xl = cx * s, yl = cy * s;
        float fx = floorf(xl), fy = floorf(yl);
        X0s[tid] = (int)fx;
        Y0s[tid] = (int)fy;
        wxs[tid] = xl - fx;
        wys[tid] = yl - fy;
    }
    __syncthreads();

#pragma unroll
    for (int r = 0; r < 7; r++) {
        int e = r * 256 + tid;
        if (e < 16 * 100) {
            int qi = e / 100;
            int el = e - qi * 100;
            int v = el / 10;
            int u = el - v * 10;
            int xx = X0s[qi] - 4 + u;
            int yy = Y0s[qi] - 4 + v;
            float val = 0.f;
            if ((unsigned)xx < (unsigned)Wl && (unsigned)yy < (unsigned)Wl)
                val = bf2f(compact[((size_t)b * NQ + g * 16 + qi) * 400
                                   + lvl * 100 + el]);
            Dl[qi * 101 + el] = val;
        }
    }
    __syncthreads();

#pragma unroll
    for (int r = 0; r < 6; r++) {
        int e = r * 256 + tid;
        if (e < 16 * 81) {
            int qi = e & 15;
            int c = e >> 4;
            int i = c / 9;            // x-offset grid index
            int j = c - i * 9;        // y-offset grid index
            float wx = wxs[qi], wy = wys[qi];
            const float* dq = &Dl[qi * 101];
            float d00 = dq[j * 10 + i];
            float d10 = dq[j * 10 + i + 1];
            float d01 = dq[(j + 1) * 10 + i];
            float d11 = dq[(j + 1) * 10 + i + 1];
            float vx0 = d00 + wx * (d10 - d00);
            float vx1 = d01 + wx * (d11 - d01);
            float val = vx0 + wy * (vx1 - vx0);
            out[((size_t)b * NCH + lvl * 81 + c) * NQ + g * 16 + qi] = val;
        }
    }
}

extern "C" void kernel_launch(void* const* d_in, const int* in_sizes, int n_in,
                              void* d_out, int out_size, void* d_ws, size_t ws_size,
                              hipStream_t stream)
{
    const float* fmap1  = (const float*)d_in[0];
    const float* fmap2  = (const float*)d_in[1];
    const float* coords = (const float*)d_in[2];
    float* out = (float*)d_out;

    char* ws = (char*)d_ws;
    const size_t A_BYTES   = (size_t)NB * NQ * ND * 2;     //  8.4 MB
    const size_t B_BYTES   = (size_t)NB * MPAD * ND * 2;   // 11.5 MB
    const size_t CMP_BYTES = (size_t)NB * NQ * 400 * 2;    // 13.1 MB
    ushort_t* Abf  = (ushort_t*)ws;
    ushort_t* Ball = (ushort_t*)(ws + A_BYTES);
    ushort_t* cmp  = (ushort_t*)(ws + A_BYTES + B_BYTES);
    int*      tbl  = (int*)(ws + A_BYTES + B_BYTES + CMP_BYTES);

    transpose_cvt<<<dim3(64, 4, NB), 256, 0, stream>>>(
        fmap1, Abf, (size_t)ND * NQ, (size_t)NQ * ND, 0.0625f);
    transpose_cvt<<<dim3(64, 4, NB), 256, 0, stream>>>(
        fmap2, Ball, (size_t)ND * NQ, (size_t)MPAD * ND, 1.0f);

    pool_kernel<<<(NB * 1024 * ND) / 256, 256, 0, stream>>>(Ball, 32, 0,    4096);
    pool_kernel<<<(NB * 256  * ND) / 256, 256, 0, stream>>>(Ball, 16, 4096, 5120);
    pool_kernel<<<(NB * 64   * ND) / 256, 256, 0, stream>>>(Ball, 8,  5120, 5376);

    make_tbl<<<(NB * NQ) / 256, 256, 0, stream>>>(coords, tbl);

    gemm_corr<<<dim3(16 * 22 * NB), 512, 0, stream>>>(Abf, Ball, cmp, tbl);

    sample_kernel<<<dim3(256, NLVL, NB), 256, 0, stream>>>(cmp, coords, out);
}

// Round 9
// 83.943 us; speedup vs baseline: 1.2772x; 1.2772x over previous
//
#include <hip/hip_runtime.h>

typedef unsigned short ushort_t;
typedef __attribute__((ext_vector_type(8))) short bfrag;
typedef __attribute__((ext_vector_type(4))) float f4;

// B=4, D=256, H=W=64, num_levels=4, radius=4
#define NB 4
#define ND 256
#define NH 64
#define NW 64
#define NQ (NH * NW)            // 4096 queries per batch
#define MPAD 5504               // 43 * 128 rows of pooled-f2 features
#define NLVL 4
#define NCH (NLVL * 81)

__device__ __forceinline__ float bf2f(ushort_t u) {
    return __uint_as_float(((unsigned)u) << 16);
}
__device__ __forceinline__ ushort_t f2bf(float f) {
    unsigned u = __float_as_uint(f);
    unsigned r = (u + 0x7fffu + ((u >> 16) & 1u)) >> 16;
    return (ushort_t)r;
}

__device__ __forceinline__ void gload_lds16(const void* g, void* l) {
    __builtin_amdgcn_global_load_lds(
        (const __attribute__((address_space(1))) unsigned int*)g,
        (__attribute__((address_space(3))) unsigned int*)l, 16, 0, 0);
}

// ---------- kernel 1: fused transposes + window table ----------
// z 0..3: fmap1 -> Abf (scaled 1/16); z 4..7: fmap2 -> Ball; z == 8: make_tbl
__global__ __launch_bounds__(256) void pre_kernel(
    const float* __restrict__ f1, const float* __restrict__ f2,
    const float* __restrict__ coords,
    ushort_t* __restrict__ Abf, ushort_t* __restrict__ Ball,
    int* __restrict__ tbl)
{
    __shared__ float tile[64][65];
    const int tid = threadIdx.x;
    const int z = blockIdx.z;

    if (z == 8) {                       // per-(batch,level,query) window base table
        int t = (blockIdx.y * 64 + blockIdx.x) * 256 + tid;   // b*4096 + q
        int b = t >> 12, q = t & 4095;
        float cx = coords[((size_t)b * 2 + 0) * NQ + q];
        float cy = coords[((size_t)b * 2 + 1) * NQ + q];
#pragma unroll
        for (int lvl = 0; lvl < 4; lvl++) {
            float s = 1.0f / (float)(1 << lvl);
            int x0 = (int)floorf(cx * s);
            int y0 = (int)floorf(cy * s);
            tbl[((b * 4 + lvl) << 12) + q] = (x0 & 0xffff) | (y0 << 16);
        }
        return;
    }

    const int b = z & 3;
    const bool isA = (z < 4);
    const float* ib = (isA ? f1 : f2) + (size_t)b * ND * NQ;
    ushort_t* ob = isA ? (Abf + (size_t)b * NQ * ND) : (Ball + (size_t)b * MPAD * ND);
    const float scale = isA ? 0.0625f : 1.0f;
    const int n0 = blockIdx.x * 64, d0 = blockIdx.y * 64;
    const int nl = tid & 63, dg = tid >> 6;
#pragma unroll
    for (int i = 0; i < 16; i++) {
        int dl = dg + i * 4;
        tile[dl][nl] = ib[(size_t)(d0 + dl) * NQ + n0 + nl];
    }
    __syncthreads();
    const int dl = tid & 63, ng = tid >> 6;
#pragma unroll
    for (int i = 0; i < 16; i++) {
        int nn = ng + i * 4;
        ob[(size_t)(n0 + nn) * ND + d0 + dl] = f2bf(tile[dl][nn] * scale);
    }
}

// ---------- kernel 2: all 3 pyramid levels in one pass ----------
// one block per (b, 8x8 lvl0 patch); thread = d channel
__global__ __launch_bounds__(256) void pool_fused(ushort_t* __restrict__ Ball)
{
    const int d = threadIdx.x;
    const int bid = blockIdx.x;          // 0 .. NB*64-1
    const int b = bid >> 6;
    const int cell = bid & 63;
    const int Y = cell >> 3, X = cell & 7;
    ushort_t* base = Ball + (size_t)b * MPAD * ND;

    float s1[4][4];
#pragma unroll
    for (int iy = 0; iy < 4; iy++)
#pragma unroll
        for (int ix = 0; ix < 4; ix++) {
            int ry = 2 * (4 * Y + iy), rx = 2 * (4 * X + ix);
            float s = bf2f(base[(size_t)((ry    ) * 64 + rx    ) * ND + d])
                    + bf2f(base[(size_t)((ry    ) * 64 + rx + 1) * ND + d])
                    + bf2f(base[(size_t)((ry + 1) * 64 + rx    ) * ND + d])
                    + bf2f(base[(size_t)((ry + 1) * 64 + rx + 1) * ND + d]);
            s1[iy][ix] = s * 0.25f;
            base[(size_t)(4096 + (4 * Y + iy) * 32 + 4 * X + ix) * ND + d] = f2bf(s1[iy][ix]);
        }
    float s2[2][2];
#pragma unroll
    for (int iy = 0; iy < 2; iy++)
#pragma unroll
        for (int ix = 0; ix < 2; ix++) {
            float s = 0.25f * (s1[2*iy][2*ix] + s1[2*iy][2*ix+1]
                             + s1[2*iy+1][2*ix] + s1[2*iy+1][2*ix+1]);
            s2[iy][ix] = s;
            base[(size_t)(5120 + (2 * Y + iy) * 16 + 2 * X + ix) * ND + d] = f2bf(s);
        }
    float s3 = 0.25f * (s2[0][0] + s2[0][1] + s2[1][0] + s2[1][1]);
    base[(size_t)(5376 + Y * 8 + X) * ND + d] = f2bf(s3);
}

// ---------- kernel 3: 256x128-tile, 8-wave, 3-slot (prefetch-2) bf16 MFMA GEMM ----------
// grid.x = 2752 = 4 batches * 16 M-tiles * 43 col-tiles, XCD-swizzled
__global__ __launch_bounds__(512, 4) void gemm_corr(
    const ushort_t* __restrict__ A,     // [NB][4096][256] bf16 (pre-scaled by 1/16)
    const ushort_t* __restrict__ Bm,    // [NB][MPAD][256] bf16
    ushort_t* __restrict__ compact,     // [NB][4096][400] bf16
    const int* __restrict__ tbl)        // [NB][4][4096] packed (x0,y0)
{
    __shared__ ushort_t As[3][256 * 32];    // 48 KiB
    __shared__ ushort_t Bs[3][128 * 32];    // 24 KiB

    // bijective XCD-chunk swizzle: 2752 = 8 * 344
    const int l   = blockIdx.x;
    const int wg  = (l & 7) * 344 + (l >> 3);
    const int z   = wg / 688;
    const int rem = wg - z * 688;
    const int by  = rem / 43;               // 0..15 (256-row M tiles)
    const int bxt = rem - by * 43;          // 0..42 (128-col tiles)

    int lvl, mbase;
    if (bxt < 32)      { lvl = 0; mbase = bxt * 128; }
    else if (bxt < 40) { lvl = 1; mbase = 4096 + (bxt - 32) * 128; }
    else if (bxt < 42) { lvl = 2; mbase = 5120 + (bxt - 40) * 128; }
    else               { lvl = 3; mbase = 5376; }

    const int tid  = threadIdx.x;
    const int lane = tid & 63;
    const int wv   = tid >> 6;              // 0..7
    const int wr   = wv >> 1;               // 0..3: rows wr*64..+64
    const int wc   = wv & 1;                // 0..1: cols wc*64..+64
    const int ln15 = lane & 15;
    const int g4   = lane >> 4;

    const ushort_t* Ab = A  + ((size_t)z * NQ   + (size_t)by * 256) * ND;
    const ushort_t* Bb = Bm + ((size_t)z * MPAD + (size_t)mbase) * ND;

    f4 acc[4][4] = {};

    // staging: A = 1024 chunks (thread t stages chunks t, t+512), B = 512 chunks
    const int rA  = tid >> 2;               // A row 0..127 (and +128)
    const int chA = (tid & 3) ^ ((tid >> 3) & 3);   // inverse-swizzled 16B chunk
    const ushort_t* srcA0 = Ab + (size_t)rA * ND + chA * 8;
    const ushort_t* srcA1 = srcA0 + (size_t)128 * ND;
    const ushort_t* srcB  = Bb + (size_t)rA * ND + chA * 8;   // B row = rA (0..127)

#define STAGE(buf, kk) {                                                   \
    gload_lds16(srcA0 + (kk), &As[buf][tid * 8]);                          \
    gload_lds16(srcA1 + (kk), &As[buf][(512 + tid) * 8]);                  \
    gload_lds16(srcB  + (kk), &Bs[buf][tid * 8]); }

    const int kch = ((lane >> 4) ^ ((ln15 >> 1) & 3)) * 8;   // swizzled read slot

    STAGE(0, 0);
    STAGE(1, 32);
    STAGE(2, 64);

#pragma unroll
    for (int t = 0; t < 8; ++t) {
        const int cur = t % 3;
        // needed slot's loads are 2 K-steps old -> near-zero stall
        if (t < 6)       { asm volatile("s_waitcnt vmcnt(6)" ::: "memory"); }
        else if (t == 6) { asm volatile("s_waitcnt vmcnt(3)" ::: "memory"); }
        else             { asm volatile("s_waitcnt vmcnt(0)" ::: "memory"); }
        __builtin_amdgcn_s_barrier();        // #1: slot `cur` fully staged
        asm volatile("" ::: "memory");

        bfrag a[4], bb[4];
#pragma unroll
        for (int mi = 0; mi < 4; mi++)
            a[mi] = *reinterpret_cast<const bfrag*>(
                &As[cur][(wr * 64 + mi * 16 + ln15) * 32 + kch]);
#pragma unroll
        for (int ni = 0; ni < 4; ni++)
            bb[ni] = *reinterpret_cast<const bfrag*>(
                &Bs[cur][(wc * 64 + ni * 16 + ln15) * 32 + kch]);

        if (t < 5) {
            __builtin_amdgcn_sched_barrier(0);                    // pin ds_reads above
            asm volatile("s_waitcnt lgkmcnt(0)" ::: "memory");    // my reads complete
            __builtin_amdgcn_s_barrier();     // #2: all waves done reading slot `cur`
            asm volatile("" ::: "memory");
            STAGE(cur, (t + 3) * 32);         // overwrite slot `cur` with K-step t+3
        }

#pragma unroll
        for (int mi = 0; mi < 4; mi++)
#pragma unroll
            for (int ni = 0; ni < 4; ni++)
                acc[mi][ni] = __builtin_amdgcn_mfma_f32_16x16x32_bf16(
                    a[mi], bb[ni], acc[mi][ni], 0, 0, 0);
    }
#undef STAGE

    // ---- compacted epilogue, geometry-aware per level (identical to R7 logic) ----
    const int row_base = by * 256 + wr * 64 + (g4 << 2);
    const int* tb      = tbl + (((size_t)z * 4 + lvl) << 12);
    ushort_t* cmp      = compact + (size_t)z * NQ * 400 + lvl * 100;

    auto for_q = [&](auto body) {
#pragma unroll
        for (int mi = 0; mi < 4; mi++) {
            const int q0 = row_base + mi * 16;
            const int4 xy4 = *reinterpret_cast<const int4*>(&tb[q0]);
            const int xys[4] = {xy4.x, xy4.y, xy4.z, xy4.w};
#pragma unroll
            for (int j = 0; j < 4; j++) {
                const int xy = xys[j];
                body(mi, j, xy & 0xffff, xy >> 16, (size_t)(q0 + j) * 400);
            }
        }
    };

    if (lvl == 0) {
        const int yfix = bxt * 2 + wc;           // y constant per thread
        for_q([&](int mi, int j, int x0, int y0, size_t qb) {
            unsigned v = (unsigned)(yfix - y0 + 4);
            if (v < 10u) {
                size_t vb = qb + v * 10;
#pragma unroll
                for (int ni = 0; ni < 4; ni++) {
                    unsigned u = (unsigned)(ln15 + 16 * ni + 4 - x0);
                    if (u < 10u) cmp[vb + u] = f2bf(acc[mi][ni][j]);
                }
            }
        });
    } else if (lvl == 1) {
        const int ybase = (bxt - 32) * 4 + wc * 2;
        for_q([&](int mi, int j, int x0, int y0, size_t qb) {
            unsigned u0 = (unsigned)(ln15 + 4 - x0), u1 = u0 + 16u;
            unsigned v0 = (unsigned)(ybase - y0 + 4), v1 = v0 + 1u;
            if (v0 < 10u) {
                if (u0 < 10u) cmp[qb + v0 * 10 + u0] = f2bf(acc[mi][0][j]);
                if (u1 < 10u) cmp[qb + v0 * 10 + u1] = f2bf(acc[mi][1][j]);
            }
            if (v1 < 10u) {
                if (u0 < 10u) cmp[qb + v1 * 10 + u0] = f2bf(acc[mi][2][j]);
                if (u1 < 10u) cmp[qb + v1 * 10 + u1] = f2bf(acc[mi][3][j]);
            }
        });
    } else if (lvl == 2) {
        const int ybase = (bxt - 40) * 8 + wc * 4;
        for_q([&](int mi, int j, int x0, int y0, size_t qb) {
            unsigned u = (unsigned)(ln15 + 4 - x0);
            if (u < 10u) {
#pragma unroll
                for (int ni = 0; ni < 4; ni++) {
                    unsigned v = (unsigned)(ybase + ni - y0 + 4);
                    if (v < 10u) cmp[qb + v * 10 + u] = f2bf(acc[mi][ni][j]);
                }
            }
        });
    } else if (wc == 0) {                        // lvl 3: cols 64..127 are pad
        const int yb3 = ln15 >> 3;
        for_q([&](int mi, int j, int x0, int y0, size_t qb) {
            unsigned u = (unsigned)((ln15 & 7) + 4 - x0);
            if (u < 10u) {
#pragma unroll
                for (int ni = 0; ni < 4; ni++) {
                    unsigned v = (unsigned)(yb3 + 2 * ni - y0 + 4);
                    if (v < 10u) cmp[qb + v * 10 + u] = f2bf(acc[mi][ni][j]);
                }
            }
        });
    }
}

// ---------- kernel 4: bilinear sampling from the compact window buffer ----------
__global__ __launch_bounds__(256) void sample_kernel(
    const ushort_t* __restrict__ compact,  // [NB][4096][400] bf16
    const float* __restrict__ coords,
    float* __restrict__ out)               // [NB][324][64][64] f32
{
    __shared__ int   X0s[16], Y0s[16];
    __shared__ float wxs[16], wys[16];
    __shared__ float Dl[16 * 101];
    const int tid = threadIdx.x;
    const int g   = blockIdx.x;
    const int lvl = blockIdx.y;
    const int b   = blockIdx.z;
    const int Wl  = NW >> lvl;

    if (tid < 16) {
        int q = g * 16 + tid;
        float cx = coords[(size_t)(b * 2 + 0) * NQ + q];
        float cy = coords[(size_t)(b * 2 + 1) * NQ + q];
        float s = 1.0f / (float)(1 << lvl);
        float xl = cx * s, yl = cy * s;
        float fx = floorf(xl), fy = floorf(yl);
        X0s[tid] = (int)fx;
        Y0s[tid] = (int)fy;
        wxs[tid] = xl - fx;
        wys[tid] = yl - fy;
    }
    __syncthreads();

#pragma unroll
    for (int r = 0; r < 7; r++) {
        int e = r * 256 + tid;
        if (e < 16 * 100) {
            int qi = e / 100;
            int el = e - qi * 100;
            int v = el / 10;
            int u = el - v * 10;
            int xx = X0s[qi] - 4 + u;
            int yy = Y0s[qi] - 4 + v;
            float val = 0.f;
            if ((unsigned)xx < (unsigned)Wl && (unsigned)yy < (unsigned)Wl)
                val = bf2f(compact[((size_t)b * NQ + g * 16 + qi) * 400
                                   + lvl * 100 + el]);
            Dl[qi * 101 + el] = val;
        }
    }
    __syncthreads();

#pragma unroll
    for (int r = 0; r < 6; r++) {
        int e = r * 256 + tid;
        if (e < 16 * 81) {
            int qi = e & 15;
            int c = e >> 4;
            int i = c / 9;            // x-offset grid index
            int j = c - i * 9;        // y-offset grid index
            float wx = wxs[qi], wy = wys[qi];
            const float* dq = &Dl[qi * 101];
            float d00 = dq[j * 10 + i];
            float d10 = dq[j * 10 + i + 1];
            float d01 = dq[(j + 1) * 10 + i];
            float d11 = dq[(j + 1) * 10 + i + 1];
            float vx0 = d00 + wx * (d10 - d00);
            float vx1 = d01 + wx * (d11 - d01);
            float val = vx0 + wy * (vx1 - vx0);
            out[((size_t)b * NCH + lvl * 81 + c) * NQ + g * 16 + qi] = val;
        }
    }
}

extern "C" void kernel_launch(void* const* d_in, const int* in_sizes, int n_in,
                              void* d_out, int out_size, void* d_ws, size_t ws_size,
                              hipStream_t stream)
{
    const float* fmap1  = (const float*)d_in[0];
    const float* fmap2  = (const float*)d_in[1];
    const float* coords = (const float*)d_in[2];
    float* out = (float*)d_out;

    char* ws = (char*)d_ws;
    const size_t A_BYTES   = (size_t)NB * NQ * ND * 2;     //  8.4 MB
    const size_t B_BYTES   = (size_t)NB * MPAD * ND * 2;   // 11.3 MB
    const size_t CMP_BYTES = (size_t)NB * NQ * 400 * 2;    // 13.1 MB
    ushort_t* Abf  = (ushort_t*)ws;
    ushort_t* Ball = (ushort_t*)(ws + A_BYTES);
    ushort_t* cmp  = (ushort_t*)(ws + A_BYTES + B_BYTES);
    int*      tbl  = (int*)(ws + A_BYTES + B_BYTES + CMP_BYTES);

    pre_kernel<<<dim3(64, 4, 9), 256, 0, stream>>>(fmap1, fmap2, coords, Abf, Ball, tbl);

    pool_fused<<<NB * 64, 256, 0, stream>>>(Ball);

    gemm_corr<<<dim3(16 * 43 * NB), 512, 0, stream>>>(Abf, Ball, cmp, tbl);

    sample_kernel<<<dim3(256, NLVL, NB), 256, 0, stream>>>(cmp, coords, out);
}